// Round 14
// baseline (287.902 us; speedup 1.0000x reference)
//
#include <hip/hip_runtime.h>
#include <hip/hip_bf16.h>
#include <cstddef>
#include <cstdint>

#define T_DIM 4096
#define B_DIM 8
#define N_DIM 256
#define H_DIM 512
#define NT_DIM 5

typedef __attribute__((ext_vector_type(8))) short short8;
typedef __attribute__((ext_vector_type(4))) float f32x4;

__device__ __forceinline__ short cvt_bf16(float f) {
  __hip_bfloat16 h = __float2bfloat16(f);
  union { __hip_bfloat16 h; short s; } u; u.h = h; return u.s;
}
__device__ __forceinline__ float bf2f(short s) {
  union { uint32_t u; float f; } v; v.u = ((uint32_t)(uint16_t)s) << 16;
  return v.f;
}

// async global->LDS, 16B/lane; LDS dest = wave-uniform base + lane*16
typedef __attribute__((address_space(1))) const void gvoid_t;
typedef __attribute__((address_space(3))) void lvoid_t;
__device__ __forceinline__ void gl_lds16(const void* g, void* lds_wave_base) {
  __builtin_amdgcn_global_load_lds((gvoid_t*)(uintptr_t)g,
                                   (lvoid_t*)(uint32_t)(uintptr_t)lds_wave_base,
                                   16, 0, 0);
}

#define MFMA16(a, b, c) __builtin_amdgcn_mfma_f32_16x16x32_bf16(a, b, c, 0, 0, 0)

// multi-slot pointer set: slot = z >> zlog, zz = z & mask.  R = bf16 residual.
struct GP {
  const short* A[4];
  const short* B[4];
  void* C[4];
  const short* R[4];
};

// ---------------------------------------------------------------------------
// TN GEMM (bf16 A/B): C[m,n] = scale * sum_k A[m,k] * Bt[n,k]  (+ bf16 Res)
// 128x128 tile, 4 waves, BK=32, 3-deep counted-vmcnt global_load_lds pipeline
// (proven r7/r8).  FLAT=true: 1D grid + XCD-chunk swizzle (T1), y-fastest.
// Epilogue: per-wave LDS restage -> coalesced dwordx4/short8 IO, Res pipelined.
// ---------------------------------------------------------------------------
template<typename TC, bool ADD_RES, bool FLAT = false>
__global__ __launch_bounds__(256)
void gemm_tn(GP p, int zlog, long long a_bs, int lda,
             long long b_bs, int ldb, long long c_bs, int ldc,
             int K, float scale, int NX = 1, int NY = 1) {
  constexpr int AB = 128 * 32 * 2;
  constexpr int BB = 128 * 32 * 2;
  constexpr int HALF = AB + BB;
  constexpr int EPIB = 4 * 16 * 68 * 4;
  constexpr int BODYB = 3 * HALF;
  constexpr int SMEMB = BODYB > EPIB ? BODYB : EPIB;
  __shared__ __align__(16) char smem[SMEMB];

  int bx, by, zidx;
  if constexpr (FLAT) {
    const int q = gridDim.x >> 3;                       // grid %8 == 0
    const int lid = (blockIdx.x & 7) * q + (blockIdx.x >> 3);
    zidx = lid / (NX * NY);
    const int rem = lid - zidx * (NX * NY);
    bx = rem / NY;
    by = rem - bx * NY;
  } else {
    bx = blockIdx.x; by = blockIdx.y; zidx = blockIdx.z;
  }

  const int dom = zidx >> zlog;
  const long long zz = zidx & ((1u << zlog) - 1u);

  const int tid  = threadIdx.x;
  const int lane = tid & 63;
  const int wave = tid >> 6;
  const int wr   = (wave >> 1) * 64;
  const int wc   = (wave & 1) * 64;
  const int lrow = lane & 15;
  const int kgrp = lane >> 4;

  const short* Abase = p.A[dom] + zz * a_bs + (long long)(bx * 128) * lda;
  const short* Bbase = p.B[dom] + zz * b_bs + (long long)(by * 128) * ldb;

  const int ch_r  = lane >> 2;
  const int swcol = ((lane & 3) ^ (ch_r & 3)) * 8;

  f32x4 acc[4][4] = {};

  auto stageA = [&](int buf, int k0) {
    short* As = (short*)(smem + buf * HALF);
    #pragma unroll
    for (int i = 0; i < 2; ++i) {
      const int c = wave + 4 * i;
      gl_lds16(Abase + (long long)(c * 16 + ch_r) * lda + k0 + swcol, &As[c * 512]);
    }
  };
  auto stageB = [&](int buf, int k0) {
    short* Bs = (short*)(smem + buf * HALF + AB);
    #pragma unroll
    for (int i = 0; i < 2; ++i) {
      const int c = wave + 4 * i;
      gl_lds16(Bbase + (long long)(c * 16 + ch_r) * ldb + k0 + swcol, &Bs[c * 512]);
    }
  };
  auto compute = [&](int buf) {
    const short* As = (const short*)(smem + buf * HALF);
    const short* Bs = (const short*)(smem + buf * HALF + AB);
    short8 af[4], bfr[4];
    const int u = kgrp ^ (lrow & 3);
    #pragma unroll
    for (int i = 0; i < 4; ++i) {
      const int row = wr + i * 16 + lrow;
      af[i] = *(const short8*)&As[row * 32 + u * 8];
    }
    #pragma unroll
    for (int j = 0; j < 4; ++j) {
      const int row = wc + j * 16 + lrow;
      bfr[j] = *(const short8*)&Bs[row * 32 + u * 8];
    }
    #pragma unroll
    for (int i = 0; i < 4; ++i)
      #pragma unroll
      for (int j = 0; j < 4; ++j)
        acc[i][j] = MFMA16(af[i], bfr[j], acc[i][j]);
  };

  const int NT = K >> 5;
  stageA(0, 0); stageB(0, 0);
  if (NT > 1) { stageA(1, 32); stageB(1, 32); }
  for (int t = 0; t < NT; ++t) {
    __builtin_amdgcn_s_barrier();
    if (t + 2 < NT) {
      stageA((t + 2) % 3, (t + 2) << 5);
      stageB((t + 2) % 3, (t + 2) << 5);
      __builtin_amdgcn_sched_barrier(0);
      asm volatile("s_waitcnt vmcnt(8)" ::: "memory");
    } else if (t + 1 < NT) {
      asm volatile("s_waitcnt vmcnt(4)" ::: "memory");
    } else {
      asm volatile("s_waitcnt vmcnt(0)" ::: "memory");
    }
    __builtin_amdgcn_sched_barrier(0);
    __builtin_amdgcn_s_barrier();
    __builtin_amdgcn_sched_barrier(0);
    compute(t % 3);
  }

  // ---- epilogue ----
  __syncthreads();
  float* myEp = (float*)smem + wave * (16 * 68);
  TC* Cd = (TC*)p.C[dom];
  const short* Res = p.R[dom];
  const long long cb = zz * c_bs;
  const int gm = bx * 128 + wr;
  const int gn = by * 128 + wc;
  const int er = lane >> 2;
  const int ec = (lane & 3) * 16;

  short8 rA0, rA1, rB0, rB1;
  if constexpr (ADD_RES) {
    const long long b0 = cb + (long long)(gm + er) * ldc + gn + ec;
    rA0 = *(const short8*)&Res[b0];
    rA1 = *(const short8*)&Res[b0 + 8];
  }

  #pragma unroll
  for (int i = 0; i < 4; ++i) {
    if constexpr (ADD_RES) {
      if (i < 3) {
        const long long bn = cb + (long long)(gm + (i + 1) * 16 + er) * ldc + gn + ec;
        rB0 = *(const short8*)&Res[bn];
        rB1 = *(const short8*)&Res[bn + 8];
      }
    }
    #pragma unroll
    for (int j = 0; j < 4; ++j)
      #pragma unroll
      for (int r = 0; r < 4; ++r)
        myEp[(kgrp * 4 + r) * 68 + j * 16 + lrow] = acc[i][j][r];
    float vals[16];
    #pragma unroll
    for (int q = 0; q < 4; ++q) {
      f32x4 t4 = *(const f32x4*)&myEp[er * 68 + ec + q * 4];
      vals[q * 4 + 0] = t4[0]; vals[q * 4 + 1] = t4[1];
      vals[q * 4 + 2] = t4[2]; vals[q * 4 + 3] = t4[3];
    }
    const int row_g = gm + i * 16 + er;
    const long long base = cb + (long long)row_g * ldc + gn + ec;
    if constexpr (sizeof(TC) == 2) {
      short8 s0, s1;
      #pragma unroll
      for (int e = 0; e < 8; ++e) {
        s0[e] = cvt_bf16(vals[e] * scale);
        s1[e] = cvt_bf16(vals[8 + e] * scale);
      }
      *(short8*)&Cd[base]     = s0;
      *(short8*)&Cd[base + 8] = s1;
    } else {
      #pragma unroll
      for (int q = 0; q < 4; ++q) {
        f32x4 o;
        #pragma unroll
        for (int e = 0; e < 4; ++e) {
          float v = vals[q * 4 + e] * scale;
          if constexpr (ADD_RES) {
            const int col = q * 4 + e;
            v += bf2f(col < 8 ? rA0[col & 7] : rA1[col & 7]);
          }
          o[e] = v;
        }
        *(f32x4*)&Cd[base + q * 4] = o;
      }
    }
    if constexpr (ADD_RES) { rA0 = rB0; rA1 = rB1; }
  }
}

// ---------------------------------------------------------------------------
// Merged prep kernel (ILP-fixed): each copy block converts 8192 elements,
// 32 per thread via 8 independent f32x4 loads (G7/G11 — BW-bound not
// latency-bound).  Role dispatch on blockIdx.x:
//  [0,192):     w6 raw cvt       (6 mats x 32 blocks)
//  [192,704):   Wo transpose cvt (2 mats x 256 blocks)
//  [704,960):   action cvt       (2 doms x 128 blocks)
//  [960,5056):  frame cvt        (2 doms x 2048 blocks)
//  [5056]:      task heads
// ---------------------------------------------------------------------------
struct PrepArgs {
  const float* w6[6];
  const float* w2[2];
  const float* av; const float* at;
  const float* fv; const float* ft;
  const float* vtask; const float* ttask;
  const float* vtw; const float* vtb;
  const float* ttw; const float* ttb;
  short* WT; short* Ac16v; short* Ac16t;
  short* Fr16v; short* Fr16t;
  float* out_vta; float* out_tta;
};

__device__ __forceinline__ void cvt_block8192(const float* __restrict__ s,
                                              short* __restrict__ d, int tid) {
  f32x4 v[8];
  #pragma unroll
  for (int j = 0; j < 4; ++j) {
    v[2 * j]     = *(const f32x4*)(s + j * 2048 + tid * 8);
    v[2 * j + 1] = *(const f32x4*)(s + j * 2048 + tid * 8 + 4);
  }
  #pragma unroll
  for (int j = 0; j < 4; ++j) {
    short8 o;
    #pragma unroll
    for (int e = 0; e < 4; ++e) {
      o[e]     = cvt_bf16(v[2 * j][e]);
      o[4 + e] = cvt_bf16(v[2 * j + 1][e]);
    }
    *(short8*)&d[j * 2048 + tid * 8] = o;
  }
}

__global__ __launch_bounds__(256)
void prep_kernel(PrepArgs a) {
  __shared__ float tile[32][33];
  const long long WS = (long long)H_DIM * H_DIM;
  const int bx = blockIdx.x;
  const int tid = threadIdx.x;

  if (bx < 192) {               // raw weight cvt: 32 blocks per matrix
    const int w = bx >> 5;
    const int blk = bx & 31;
    cvt_block8192(a.w6[w] + blk * 8192, a.WT + (long long)w * WS + blk * 8192, tid);
  } else if (bx < 704) {        // Wo transpose cvt
    const int r = bx - 192;
    const int w = r >> 8;
    const int rem = r & 255;
    const int n0 = (rem >> 4) * 32, k0 = (rem & 15) * 32;
    const float* src = a.w2[w];
    short* d = a.WT + (long long)(6 + w) * WS;
    const int tx = tid & 31, ty = tid >> 5;
    #pragma unroll
    for (int i = 0; i < 4; ++i)
      tile[ty + 8 * i][tx] = src[(long long)(k0 + ty + 8 * i) * H_DIM + n0 + tx];
    __syncthreads();
    #pragma unroll
    for (int i = 0; i < 4; ++i)
      d[(long long)(n0 + ty + 8 * i) * H_DIM + k0 + tx] = cvt_bf16(tile[tx][ty + 8 * i]);
  } else if (bx < 960) {        // action cvt: 128 blocks per domain
    const int r = bx - 704;
    const int dom = r >> 7;
    const int blk = r & 127;
    const float* src = dom ? a.at : a.av;
    short* d = dom ? a.Ac16t : a.Ac16v;
    cvt_block8192(src + blk * 8192, d + blk * 8192, tid);
  } else if (bx < 5056) {       // frame cvt: 2048 blocks per domain
    const int r = bx - 960;
    const int dom = r >> 11;
    const int blk = r & 2047;
    const float* src = dom ? a.ft : a.fv;
    short* d = dom ? a.Fr16t : a.Fr16v;
    cvt_block8192(src + (long long)blk * 8192, d + (long long)blk * 8192, tid);
  } else {                      // task heads
    const int wave = tid >> 6;
    const int lane = tid & 63;
    for (int g = wave; g < 16; g += 4) {
      const int dom = g >> 3;
      const int b = g & 7;
      const float* task = dom ? a.ttask : a.vtask;
      const float* tw   = dom ? a.ttw : a.vtw;
      const float  tb   = (dom ? a.ttb : a.vtb)[0];
      float* o = dom ? a.out_tta : a.out_vta;
      for (int k = 0; k < NT_DIM; ++k) {
        const float* row = task + ((long long)k * B_DIM + b) * H_DIM;
        float s = 0.f;
        for (int c = lane; c < H_DIM; c += 64) s += row[c] * tw[c];
        #pragma unroll
        for (int d2 = 32; d2 > 0; d2 >>= 1) s += __shfl_xor(s, d2);
        if (lane == 0) o[k * B_DIM + b] = s + tb;
      }
    }
  }
}

// ---------------------------------------------------------------------------
// Fused: combine + masked softmax + bf16 attn + nomask transpose (r6 proven)
// ---------------------------------------------------------------------------
__global__ __launch_bounds__(256)
void softmax_fused(const short* __restrict__ Lv, const short* __restrict__ Lt,
                   const int* __restrict__ vmask, const int* __restrict__ tmask,
                   const float* __restrict__ vaw, const float* __restrict__ taw,
                   short* __restrict__ Av, short* __restrict__ At,
                   float* __restrict__ Onm_v, float* __restrict__ Onm_t) {
  __shared__ float tile[16 * 260];
  __shared__ int msk[2][256];
  const int tid = threadIdx.x;
  const int b = blockIdx.y, t0 = blockIdx.x * 16;
  const int r = tid >> 4, seg = tid & 15;
  msk[0][tid] = vmask[b * 256 + tid];
  msk[1][tid] = tmask[b * 256 + tid];
  __syncthreads();
  const float sv = 1.f / (1.f + __expf(-vaw[0]));
  const float st = 1.f / (1.f + __expf(-taw[0]));
  const long long off = ((long long)b * T_DIM + t0 + r) * N_DIM + seg * 16;

  short8 lv0 = *(const short8*)&Lv[off];
  short8 lv1 = *(const short8*)&Lv[off + 8];
  short8 lt0 = *(const short8*)&Lt[off];
  short8 lt1 = *(const short8*)&Lt[off + 8];
  float cv[16], ct[16];
  #pragma unroll
  for (int i = 0; i < 8; ++i) {
    float a0 = bf2f(lv0[i]), b0 = bf2f(lt0[i]);
    float a1 = bf2f(lv1[i]), b1 = bf2f(lt1[i]);
    cv[i]     = a0 + sv * b0;  ct[i]     = b0 + st * a0;
    cv[8 + i] = a1 + sv * b1;  ct[8 + i] = b1 + st * a1;
  }

#define EMIT_DOMAIN(CVAL, DI, AOUT, ONM) do {                                   \
    const int4 mA = *(const int4*)&msk[DI][seg * 16 + 0];                       \
    const int4 mB = *(const int4*)&msk[DI][seg * 16 + 4];                       \
    const int4 mC = *(const int4*)&msk[DI][seg * 16 + 8];                       \
    const int4 mD = *(const int4*)&msk[DI][seg * 16 + 12];                      \
    const int mk[16] = {mA.x, mA.y, mA.z, mA.w, mB.x, mB.y, mB.z, mB.w,         \
                        mC.x, mC.y, mC.z, mC.w, mD.x, mD.y, mD.z, mD.w};        \
    float mx = -3.4e38f;                                                        \
    _Pragma("unroll")                                                           \
    for (int q = 0; q < 16; ++q) if (mk[q] > 0) mx = fmaxf(mx, CVAL[q]);        \
    _Pragma("unroll")                                                           \
    for (int sh = 1; sh < 16; sh <<= 1) mx = fmaxf(mx, __shfl_xor(mx, sh));     \
    float ev[16]; float ssum = 0.f;                                             \
    _Pragma("unroll")                                                           \
    for (int q = 0; q < 16; ++q) {                                              \
      ev[q] = (mk[q] > 0) ? __expf(CVAL[q] - mx) : 0.f; ssum += ev[q];          \
    }                                                                           \
    _Pragma("unroll")                                                           \
    for (int sh = 1; sh < 16; sh <<= 1) ssum += __shfl_xor(ssum, sh);           \
    const float inv = 1.f / ssum;                                               \
    short8 o0, o1;                                                              \
    _Pragma("unroll")                                                           \
    for (int q = 0; q < 8; ++q) {                                               \
      o0[q] = cvt_bf16(ev[q] * inv); o1[q] = cvt_bf16(ev[8 + q] * inv);         \
    }                                                                           \
    *(short8*)&AOUT[off] = o0; *(short8*)&AOUT[off + 8] = o1;                   \
    _Pragma("unroll")                                                           \
    for (int q = 0; q < 4; ++q) {                                               \
      f32x4 tv; tv[0] = CVAL[q * 4]; tv[1] = CVAL[q * 4 + 1];                   \
      tv[2] = CVAL[q * 4 + 2]; tv[3] = CVAL[q * 4 + 3];                         \
      *(f32x4*)&tile[r * 260 + seg * 16 + q * 4] = tv;                          \
    }                                                                           \
    __syncthreads();                                                            \
    {                                                                           \
      float* obase = &ONM[((long long)b * N_DIM + tid) * T_DIM + t0];           \
      _Pragma("unroll")                                                         \
      for (int g = 0; g < 4; ++g) {                                             \
        f32x4 wv;                                                               \
        wv[0] = tile[(4 * g + 0) * 260 + tid];                                  \
        wv[1] = tile[(4 * g + 1) * 260 + tid];                                  \
        wv[2] = tile[(4 * g + 2) * 260 + tid];                                  \
        wv[3] = tile[(4 * g + 3) * 260 + tid];                                  \
        *(f32x4*)&obase[4 * g] = wv;                                            \
      }                                                                         \
    }                                                                           \
    __syncthreads();                                                            \
  } while (0)

  EMIT_DOMAIN(cv, 0, Av, Onm_v);
  EMIT_DOMAIN(ct, 1, At, Onm_t);
#undef EMIT_DOMAIN
}

// ---------------------------------------------------------------------------
extern "C" void kernel_launch(void* const* d_in, const int* in_sizes, int n_in,
                              void* d_out, int out_size, void* d_ws, size_t ws_size,
                              hipStream_t stream) {
  const float* v_action = (const float*)d_in[0];
  const float* v_frame  = (const float*)d_in[1];
  const float* v_task   = (const float*)d_in[2];
  const int*   v_mask   = (const int*)d_in[3];
  const float* t_action = (const float*)d_in[4];
  const float* t_frame  = (const float*)d_in[5];
  const float* t_task   = (const float*)d_in[6];
  const int*   t_mask   = (const int*)d_in[7];
  const float* v_aw = (const float*)d_in[16];
  const float* t_aw = (const float*)d_in[17];
  const float* v_tw = (const float*)d_in[18];
  const float* v_tb = (const float*)d_in[19];
  const float* t_tw = (const float*)d_in[20];
  const float* t_tb = (const float*)d_in[21];

  const long long TBH = (long long)T_DIM * B_DIM * H_DIM;
  const long long BTN = (long long)B_DIM * T_DIM * N_DIM;
  const long long WS  = (long long)H_DIM * H_DIM;     // 262144

  float* out = (float*)d_out;
  float* out_v   = out;
  float* out_t   = out + TBH;
  float* out_vnm = out + 2 * TBH;
  float* out_tnm = out + 2 * TBH + BTN;
  float* out_vta = out + 2 * TBH + 2 * BTN;
  float* out_tta = out_vta + NT_DIM * B_DIM;

  char* w = (char*)d_ws;
  auto alloc = [&](long long bytes) {
    char* p = w; w += (bytes + 255) & ~255LL; return p;
  };
  // WT slots: 0 WQv,1 WKv,2 WVv,3 WQt,4 WKt,5 WVt (raw), 6 WoTv,7 WoTt (trans)
  short* WT    = (short*)alloc(8 * WS * 2);
  short* Mv    = (short*)alloc(WS * 2);
  short* Mt    = (short*)alloc(WS * 2);
  short* PTv   = (short*)alloc(WS * 2);
  short* PTt   = (short*)alloc(WS * 2);
  short* Ac16v = (short*)alloc(1048576LL * 2);
  short* Ac16t = (short*)alloc(1048576LL * 2);
  short* Fr16v = (short*)alloc(TBH * 2);
  short* Fr16t = (short*)alloc(TBH * 2);
  short* KWTv  = (short*)alloc(8LL * 131072 * 2);  // [b][n][f]
  short* KWTt  = (short*)alloc(8LL * 131072 * 2);
  short* VWTv  = (short*)alloc(8LL * 131072 * 2);  // [b][g][n]
  short* VWTt  = (short*)alloc(8LL * 131072 * 2);
  short* Av    = (short*)alloc(BTN * 2);
  short* At    = (short*)alloc(BTN * 2);
  short* Lv    = (short*)alloc(BTN * 2);
  short* Lt    = (short*)alloc(BTN * 2);

  const float rsq = 0.044194173824159216f;  // 1/sqrt(512)

  // 1. merged prep: weight cvts + action/frame cvt + task heads
  {
    PrepArgs a;
    a.w6[0] = (const float*)d_in[8];  a.w6[1] = (const float*)d_in[9];
    a.w6[2] = (const float*)d_in[10]; a.w6[3] = (const float*)d_in[12];
    a.w6[4] = (const float*)d_in[13]; a.w6[5] = (const float*)d_in[14];
    a.w2[0] = (const float*)d_in[11]; a.w2[1] = (const float*)d_in[15];
    a.av = v_action; a.at = t_action;
    a.fv = v_frame;  a.ft = t_frame;
    a.vtask = v_task; a.ttask = t_task;
    a.vtw = v_tw; a.vtb = v_tb; a.ttw = t_tw; a.ttb = t_tb;
    a.WT = WT; a.Ac16v = Ac16v; a.Ac16t = Ac16t;
    a.Fr16v = Fr16v; a.Fr16t = Fr16t;
    a.out_vta = out_vta; a.out_tta = out_tta;
    prep_kernel<<<dim3(5057), dim3(256), 0, stream>>>(a);
  }

  // 2. M = Wq@Wk^T and PT = WoT@Wv, 4 slots in one launch (z=0..3, zlog=0)
  {
    GP p = {{WT + 0 * WS, WT + 3 * WS, WT + 6 * WS, WT + 7 * WS},
            {WT + 1 * WS, WT + 4 * WS, WT + 2 * WS, WT + 5 * WS},
            {Mv, Mt, PTv, PTt},
            {nullptr, nullptr, nullptr, nullptr}};
    gemm_tn<short, false><<<dim3(4, 4, 4), dim3(256), 0, stream>>>(
        p, 0, 0LL, H_DIM, 0LL, H_DIM, 0LL, H_DIM, 512, 1.f);
  }

  // 3. KWT[b][n][f] = action @ M^T  (z = dom*8+b)
  {
    GP p = {{Ac16v, Ac16t}, {Mv, Mt}, {KWTv, KWTt}, {nullptr, nullptr}};
    gemm_tn<short, false><<<dim3(2, 4, 16), dim3(256), 0, stream>>>(
        p, 3, 512LL, B_DIM * H_DIM, 0LL, H_DIM, 131072LL, H_DIM, 512, 1.f);
  }

  // 4. VWT[b][g][n] = PT @ action^T  (z = dom*8+b)
  {
    GP p = {{PTv, PTt}, {Ac16v, Ac16t}, {VWTv, VWTt}, {nullptr, nullptr}};
    gemm_tn<short, false><<<dim3(4, 2, 16), dim3(256), 0, stream>>>(
        p, 3, 0LL, H_DIM, 512LL, B_DIM * H_DIM, 131072LL, N_DIM, 512, 1.f);
  }

  // 5. logits (bf16) [B,T,N] = Fr16 @ KWT^T  (bf16 pipeline, FLAT swizzle)
  {
    GP p = {{Fr16v, Fr16t}, {KWTv, KWTt}, {Lv, Lt}, {nullptr, nullptr}};
    gemm_tn<short, false, true><<<dim3(32 * 2 * 16), dim3(256), 0, stream>>>(
        p, 3, 512LL, B_DIM * H_DIM, 131072LL, H_DIM,
        (long long)T_DIM * N_DIM, N_DIM, 512, rsq, 32, 2);
  }

  // 6. fused combine + softmax + nomask-transpose
  softmax_fused<<<dim3(T_DIM / 16, B_DIM), dim3(256), 0, stream>>>(
      Lv, Lt, v_mask, t_mask, v_aw, t_aw, Av, At, out_vnm, out_tnm);

  // 7. out = attn @ VW + Fr16  (K=256, FLAT swizzle; residual from bf16 frame)
  {
    GP p = {{Av, At}, {VWTv, VWTt}, {out_v, out_t}, {Fr16v, Fr16t}};
    gemm_tn<float, true, true><<<dim3(32 * 4 * 16), dim3(256), 0, stream>>>(
        p, 3, (long long)T_DIM * N_DIM, N_DIM, 131072LL, N_DIM,
        512LL, B_DIM * H_DIM, 256, 1.f, 32, 4);
  }
}

// Round 15
// 247.947 us; speedup vs baseline: 1.1611x; 1.1611x over previous
//
#include <hip/hip_runtime.h>
#include <hip/hip_bf16.h>
#include <cstddef>
#include <cstdint>

#define T_DIM 4096
#define B_DIM 8
#define N_DIM 256
#define H_DIM 512
#define NT_DIM 5

typedef __attribute__((ext_vector_type(8))) short short8;
typedef __attribute__((ext_vector_type(4))) float f32x4;

__device__ __forceinline__ short cvt_bf16(float f) {
  __hip_bfloat16 h = __float2bfloat16(f);
  union { __hip_bfloat16 h; short s; } u; u.h = h; return u.s;
}
__device__ __forceinline__ float bf2f(short s) {
  union { uint32_t u; float f; } v; v.u = ((uint32_t)(uint16_t)s) << 16;
  return v.f;
}

// async global->LDS, 16B/lane; LDS dest = wave-uniform base + lane*16
typedef __attribute__((address_space(1))) const void gvoid_t;
typedef __attribute__((address_space(3))) void lvoid_t;
__device__ __forceinline__ void gl_lds16(const void* g, void* lds_wave_base) {
  __builtin_amdgcn_global_load_lds((gvoid_t*)(uintptr_t)g,
                                   (lvoid_t*)(uint32_t)(uintptr_t)lds_wave_base,
                                   16, 0, 0);
}

#define MFMA16(a, b, c) __builtin_amdgcn_mfma_f32_16x16x32_bf16(a, b, c, 0, 0, 0)

// multi-slot pointer set: slot = z >> zlog, zz = z & mask.  R = bf16 residual.
struct GP {
  const short* A[4];
  const short* B[4];
  void* C[4];
  const short* R[4];
};

// ---------------------------------------------------------------------------
// TN GEMM (bf16 A/B): C[m,n] = scale * sum_k A[m,k] * Bt[n,k]  (+ bf16 Res)
// 128x128 tile, 4 waves, BK=32, 3-deep counted-vmcnt global_load_lds pipeline
// (proven r7/r8).  FLAT=true: 1D grid + XCD-chunk swizzle (T1), y-fastest.
// ---------------------------------------------------------------------------
template<typename TC, bool ADD_RES, bool FLAT = false>
__global__ __launch_bounds__(256)
void gemm_tn(GP p, int zlog, long long a_bs, int lda,
             long long b_bs, int ldb, long long c_bs, int ldc,
             int K, float scale, int NX = 1, int NY = 1) {
  constexpr int AB = 128 * 32 * 2;
  constexpr int BB = 128 * 32 * 2;
  constexpr int HALF = AB + BB;
  constexpr int EPIB = 4 * 16 * 68 * 4;
  constexpr int BODYB = 3 * HALF;
  constexpr int SMEMB = BODYB > EPIB ? BODYB : EPIB;
  __shared__ __align__(16) char smem[SMEMB];

  int bx, by, zidx;
  if constexpr (FLAT) {
    const int q = gridDim.x >> 3;                       // grid %8 == 0
    const int lid = (blockIdx.x & 7) * q + (blockIdx.x >> 3);
    zidx = lid / (NX * NY);
    const int rem = lid - zidx * (NX * NY);
    bx = rem / NY;
    by = rem - bx * NY;
  } else {
    bx = blockIdx.x; by = blockIdx.y; zidx = blockIdx.z;
  }

  const int dom = zidx >> zlog;
  const long long zz = zidx & ((1u << zlog) - 1u);

  const int tid  = threadIdx.x;
  const int lane = tid & 63;
  const int wave = tid >> 6;
  const int wr   = (wave >> 1) * 64;
  const int wc   = (wave & 1) * 64;
  const int lrow = lane & 15;
  const int kgrp = lane >> 4;

  const short* Abase = p.A[dom] + zz * a_bs + (long long)(bx * 128) * lda;
  const short* Bbase = p.B[dom] + zz * b_bs + (long long)(by * 128) * ldb;

  const int ch_r  = lane >> 2;
  const int swcol = ((lane & 3) ^ (ch_r & 3)) * 8;

  f32x4 acc[4][4] = {};

  auto stageA = [&](int buf, int k0) {
    short* As = (short*)(smem + buf * HALF);
    #pragma unroll
    for (int i = 0; i < 2; ++i) {
      const int c = wave + 4 * i;
      gl_lds16(Abase + (long long)(c * 16 + ch_r) * lda + k0 + swcol, &As[c * 512]);
    }
  };
  auto stageB = [&](int buf, int k0) {
    short* Bs = (short*)(smem + buf * HALF + AB);
    #pragma unroll
    for (int i = 0; i < 2; ++i) {
      const int c = wave + 4 * i;
      gl_lds16(Bbase + (long long)(c * 16 + ch_r) * ldb + k0 + swcol, &Bs[c * 512]);
    }
  };
  auto compute = [&](int buf) {
    const short* As = (const short*)(smem + buf * HALF);
    const short* Bs = (const short*)(smem + buf * HALF + AB);
    short8 af[4], bfr[4];
    const int u = kgrp ^ (lrow & 3);
    #pragma unroll
    for (int i = 0; i < 4; ++i) {
      const int row = wr + i * 16 + lrow;
      af[i] = *(const short8*)&As[row * 32 + u * 8];
    }
    #pragma unroll
    for (int j = 0; j < 4; ++j) {
      const int row = wc + j * 16 + lrow;
      bfr[j] = *(const short8*)&Bs[row * 32 + u * 8];
    }
    #pragma unroll
    for (int i = 0; i < 4; ++i)
      #pragma unroll
      for (int j = 0; j < 4; ++j)
        acc[i][j] = MFMA16(af[i], bfr[j], acc[i][j]);
  };

  const int NT = K >> 5;
  stageA(0, 0); stageB(0, 0);
  if (NT > 1) { stageA(1, 32); stageB(1, 32); }
  for (int t = 0; t < NT; ++t) {
    __builtin_amdgcn_s_barrier();
    if (t + 2 < NT) {
      stageA((t + 2) % 3, (t + 2) << 5);
      stageB((t + 2) % 3, (t + 2) << 5);
      __builtin_amdgcn_sched_barrier(0);
      asm volatile("s_waitcnt vmcnt(8)" ::: "memory");
    } else if (t + 1 < NT) {
      asm volatile("s_waitcnt vmcnt(4)" ::: "memory");
    } else {
      asm volatile("s_waitcnt vmcnt(0)" ::: "memory");
    }
    __builtin_amdgcn_sched_barrier(0);
    __builtin_amdgcn_s_barrier();
    __builtin_amdgcn_sched_barrier(0);
    compute(t % 3);
  }

  // ---- epilogue ----
  __syncthreads();
  float* myEp = (float*)smem + wave * (16 * 68);
  TC* Cd = (TC*)p.C[dom];
  const short* Res = p.R[dom];
  const long long cb = zz * c_bs;
  const int gm = bx * 128 + wr;
  const int gn = by * 128 + wc;
  const int er = lane >> 2;
  const int ec = (lane & 3) * 16;

  short8 rA0, rA1, rB0, rB1;
  if constexpr (ADD_RES) {
    const long long b0 = cb + (long long)(gm + er) * ldc + gn + ec;
    rA0 = *(const short8*)&Res[b0];
    rA1 = *(const short8*)&Res[b0 + 8];
  }

  #pragma unroll
  for (int i = 0; i < 4; ++i) {
    if constexpr (ADD_RES) {
      if (i < 3) {
        const long long bn = cb + (long long)(gm + (i + 1) * 16 + er) * ldc + gn + ec;
        rB0 = *(const short8*)&Res[bn];
        rB1 = *(const short8*)&Res[bn + 8];
      }
    }
    #pragma unroll
    for (int j = 0; j < 4; ++j)
      #pragma unroll
      for (int r = 0; r < 4; ++r)
        myEp[(kgrp * 4 + r) * 68 + j * 16 + lrow] = acc[i][j][r];
    float vals[16];
    #pragma unroll
    for (int q = 0; q < 4; ++q) {
      f32x4 t4 = *(const f32x4*)&myEp[er * 68 + ec + q * 4];
      vals[q * 4 + 0] = t4[0]; vals[q * 4 + 1] = t4[1];
      vals[q * 4 + 2] = t4[2]; vals[q * 4 + 3] = t4[3];
    }
    const int row_g = gm + i * 16 + er;
    const long long base = cb + (long long)row_g * ldc + gn + ec;
    if constexpr (sizeof(TC) == 2) {
      short8 s0, s1;
      #pragma unroll
      for (int e = 0; e < 8; ++e) {
        s0[e] = cvt_bf16(vals[e] * scale);
        s1[e] = cvt_bf16(vals[8 + e] * scale);
      }
      *(short8*)&Cd[base]     = s0;
      *(short8*)&Cd[base + 8] = s1;
    } else {
      #pragma unroll
      for (int q = 0; q < 4; ++q) {
        f32x4 o;
        #pragma unroll
        for (int e = 0; e < 4; ++e) {
          float v = vals[q * 4 + e] * scale;
          if constexpr (ADD_RES) {
            const int col = q * 4 + e;
            v += bf2f(col < 8 ? rA0[col & 7] : rA1[col & 7]);
          }
          o[e] = v;
        }
        *(f32x4*)&Cd[base + q * 4] = o;
      }
    }
    if constexpr (ADD_RES) { rA0 = rB0; rA1 = rB1; }
  }
}

// ---------------------------------------------------------------------------
// Raw f32->bf16 copy of 6 weight matrices (Wq,Wk,Wv both domains) [r11 proven]
// ---------------------------------------------------------------------------
struct W6 { const float* p[6]; };

__global__ __launch_bounds__(256)
void rawcvt_kernel(W6 s, short* __restrict__ dst) {
  const int w = blockIdx.y;
  const float* src = s.p[w];
  short* d = dst + (long long)w * H_DIM * H_DIM;
  const int i = (blockIdx.x * 256 + threadIdx.x) * 8;   // grid.x = 128
  f32x4 v0 = *(const f32x4*)(src + i);
  f32x4 v1 = *(const f32x4*)(src + i + 4);
  short8 o;
  #pragma unroll
  for (int e = 0; e < 4; ++e) { o[e] = cvt_bf16(v0[e]); o[4 + e] = cvt_bf16(v1[e]); }
  *(short8*)&d[i] = o;
}

// ---------------------------------------------------------------------------
// Transposed cvt for Wo (2 matrices): WoT[n][k] = bf16(Wo[k][n]) [r11 proven]
// ---------------------------------------------------------------------------
struct W2 { const float* p[2]; };

__global__ __launch_bounds__(256)
void wtrans_kernel(W2 s, short* __restrict__ dst) {
  __shared__ float tile[32][33];
  const int w = blockIdx.z;
  const float* src = s.p[w];
  short* d = dst + (long long)w * H_DIM * H_DIM;
  const int tx = threadIdx.x, ty = threadIdx.y;
  const int n0 = blockIdx.x * 32, k0 = blockIdx.y * 32;
  #pragma unroll
  for (int i = 0; i < 4; ++i)
    tile[ty + 8 * i][tx] = src[(long long)(k0 + ty + 8 * i) * H_DIM + n0 + tx];
  __syncthreads();
  #pragma unroll
  for (int i = 0; i < 4; ++i)
    d[(long long)(n0 + ty + 8 * i) * H_DIM + k0 + tx] = cvt_bf16(tile[tx][ty + 8 * i]);
}

// ---------------------------------------------------------------------------
// action f32 -> bf16 (layout preserved), both domains [r11 proven]
// ---------------------------------------------------------------------------
__global__ __launch_bounds__(256)
void ac16_kernel(const float* __restrict__ av, const float* __restrict__ at,
                 short* __restrict__ ov, short* __restrict__ ot) {
  const int dom = blockIdx.y;
  const float* src = dom ? at : av;
  short* d = dom ? ot : ov;
  const int i = (blockIdx.x * 256 + threadIdx.x) * 8;   // grid.x = 512
  f32x4 v0 = *(const f32x4*)(src + i);
  f32x4 v1 = *(const f32x4*)(src + i + 4);
  short8 o;
  #pragma unroll
  for (int e = 0; e < 4; ++e) { o[e] = cvt_bf16(v0[e]); o[4 + e] = cvt_bf16(v1[e]); }
  *(short8*)&d[i] = o;
}

// ---------------------------------------------------------------------------
// frame f32 -> bf16 (layout preserved), both domains — same pattern as ac16
// ---------------------------------------------------------------------------
__global__ __launch_bounds__(256)
void fr16_kernel(const float* __restrict__ fv, const float* __restrict__ ft,
                 short* __restrict__ ov, short* __restrict__ ot) {
  const int dom = blockIdx.y;
  const float* src = dom ? ft : fv;
  short* d = dom ? ot : ov;
  const long long i = ((long long)blockIdx.x * 256 + threadIdx.x) * 8;  // grid.x = 8192
  f32x4 v0 = *(const f32x4*)(src + i);
  f32x4 v1 = *(const f32x4*)(src + i + 4);
  short8 o;
  #pragma unroll
  for (int e = 0; e < 4; ++e) { o[e] = cvt_bf16(v0[e]); o[4 + e] = cvt_bf16(v1[e]); }
  *(short8*)&d[i] = o;
}

// ---------------------------------------------------------------------------
// Task heads [r11 proven]
// ---------------------------------------------------------------------------
__global__ __launch_bounds__(1024)
void task_kernel(const float* __restrict__ vtask, const float* __restrict__ ttask,
                 const float* __restrict__ vtw, const float* __restrict__ vtb,
                 const float* __restrict__ ttw, const float* __restrict__ ttb,
                 float* __restrict__ out_v, float* __restrict__ out_t) {
  const int wave = threadIdx.x >> 6;
  const int lane = threadIdx.x & 63;
  const int dom = wave >> 3;
  const int b   = wave & 7;
  const float* task = dom ? ttask : vtask;
  const float* tw   = dom ? ttw : vtw;
  const float  tb   = (dom ? ttb : vtb)[0];
  float* o = dom ? out_t : out_v;
  for (int k = 0; k < NT_DIM; ++k) {
    const float* row = task + ((long long)k * B_DIM + b) * H_DIM;
    float s = 0.f;
    for (int c = lane; c < H_DIM; c += 64) s += row[c] * tw[c];
    #pragma unroll
    for (int d = 32; d > 0; d >>= 1) s += __shfl_xor(s, d);
    if (lane == 0) o[k * B_DIM + b] = s + tb;
  }
}

// ---------------------------------------------------------------------------
// Fused: combine + masked softmax + bf16 attn + nomask transpose (r6 proven)
// ---------------------------------------------------------------------------
__global__ __launch_bounds__(256)
void softmax_fused(const short* __restrict__ Lv, const short* __restrict__ Lt,
                   const int* __restrict__ vmask, const int* __restrict__ tmask,
                   const float* __restrict__ vaw, const float* __restrict__ taw,
                   short* __restrict__ Av, short* __restrict__ At,
                   float* __restrict__ Onm_v, float* __restrict__ Onm_t) {
  __shared__ float tile[16 * 260];
  __shared__ int msk[2][256];
  const int tid = threadIdx.x;
  const int b = blockIdx.y, t0 = blockIdx.x * 16;
  const int r = tid >> 4, seg = tid & 15;
  msk[0][tid] = vmask[b * 256 + tid];
  msk[1][tid] = tmask[b * 256 + tid];
  __syncthreads();
  const float sv = 1.f / (1.f + __expf(-vaw[0]));
  const float st = 1.f / (1.f + __expf(-taw[0]));
  const long long off = ((long long)b * T_DIM + t0 + r) * N_DIM + seg * 16;

  short8 lv0 = *(const short8*)&Lv[off];
  short8 lv1 = *(const short8*)&Lv[off + 8];
  short8 lt0 = *(const short8*)&Lt[off];
  short8 lt1 = *(const short8*)&Lt[off + 8];
  float cv[16], ct[16];
  #pragma unroll
  for (int i = 0; i < 8; ++i) {
    float a0 = bf2f(lv0[i]), b0 = bf2f(lt0[i]);
    float a1 = bf2f(lv1[i]), b1 = bf2f(lt1[i]);
    cv[i]     = a0 + sv * b0;  ct[i]     = b0 + st * a0;
    cv[8 + i] = a1 + sv * b1;  ct[8 + i] = b1 + st * a1;
  }

#define EMIT_DOMAIN(CVAL, DI, AOUT, ONM) do {                                   \
    const int4 mA = *(const int4*)&msk[DI][seg * 16 + 0];                       \
    const int4 mB = *(const int4*)&msk[DI][seg * 16 + 4];                       \
    const int4 mC = *(const int4*)&msk[DI][seg * 16 + 8];                       \
    const int4 mD = *(const int4*)&msk[DI][seg * 16 + 12];                      \
    const int mk[16] = {mA.x, mA.y, mA.z, mA.w, mB.x, mB.y, mB.z, mB.w,         \
                        mC.x, mC.y, mC.z, mC.w, mD.x, mD.y, mD.z, mD.w};        \
    float mx = -3.4e38f;                                                        \
    _Pragma("unroll")                                                           \
    for (int q = 0; q < 16; ++q) if (mk[q] > 0) mx = fmaxf(mx, CVAL[q]);        \
    _Pragma("unroll")                                                           \
    for (int sh = 1; sh < 16; sh <<= 1) mx = fmaxf(mx, __shfl_xor(mx, sh));     \
    float ev[16]; float ssum = 0.f;                                             \
    _Pragma("unroll")                                                           \
    for (int q = 0; q < 16; ++q) {                                              \
      ev[q] = (mk[q] > 0) ? __expf(CVAL[q] - mx) : 0.f; ssum += ev[q];          \
    }                                                                           \
    _Pragma("unroll")                                                           \
    for (int sh = 1; sh < 16; sh <<= 1) ssum += __shfl_xor(ssum, sh);           \
    const float inv = 1.f / ssum;                                               \
    short8 o0, o1;                                                              \
    _Pragma("unroll")                                                           \
    for (int q = 0; q < 8; ++q) {                                               \
      o0[q] = cvt_bf16(ev[q] * inv); o1[q] = cvt_bf16(ev[8 + q] * inv);         \
    }                                                                           \
    *(short8*)&AOUT[off] = o0; *(short8*)&AOUT[off + 8] = o1;                   \
    _Pragma("unroll")                                                           \
    for (int q = 0; q < 4; ++q) {                                               \
      f32x4 tv; tv[0] = CVAL[q * 4]; tv[1] = CVAL[q * 4 + 1];                   \
      tv[2] = CVAL[q * 4 + 2]; tv[3] = CVAL[q * 4 + 3];                         \
      *(f32x4*)&tile[r * 260 + seg * 16 + q * 4] = tv;                          \
    }                                                                           \
    __syncthreads();                                                            \
    {                                                                           \
      float* obase = &ONM[((long long)b * N_DIM + tid) * T_DIM + t0];           \
      _Pragma("unroll")                                                         \
      for (int g = 0; g < 4; ++g) {                                             \
        f32x4 wv;                                                               \
        wv[0] = tile[(4 * g + 0) * 260 + tid];                                  \
        wv[1] = tile[(4 * g + 1) * 260 + tid];                                  \
        wv[2] = tile[(4 * g + 2) * 260 + tid];                                  \
        wv[3] = tile[(4 * g + 3) * 260 + tid];                                  \
        *(f32x4*)&obase[4 * g] = wv;                                            \
      }                                                                         \
    }                                                                           \
    __syncthreads();                                                            \
  } while (0)

  EMIT_DOMAIN(cv, 0, Av, Onm_v);
  EMIT_DOMAIN(ct, 1, At, Onm_t);
#undef EMIT_DOMAIN
}

// ---------------------------------------------------------------------------
extern "C" void kernel_launch(void* const* d_in, const int* in_sizes, int n_in,
                              void* d_out, int out_size, void* d_ws, size_t ws_size,
                              hipStream_t stream) {
  const float* v_action = (const float*)d_in[0];
  const float* v_frame  = (const float*)d_in[1];
  const float* v_task   = (const float*)d_in[2];
  const int*   v_mask   = (const int*)d_in[3];
  const float* t_action = (const float*)d_in[4];
  const float* t_frame  = (const float*)d_in[5];
  const float* t_task   = (const float*)d_in[6];
  const int*   t_mask   = (const int*)d_in[7];
  const float* v_aw = (const float*)d_in[16];
  const float* t_aw = (const float*)d_in[17];
  const float* v_tw = (const float*)d_in[18];
  const float* v_tb = (const float*)d_in[19];
  const float* t_tw = (const float*)d_in[20];
  const float* t_tb = (const float*)d_in[21];

  const long long TBH = (long long)T_DIM * B_DIM * H_DIM;
  const long long BTN = (long long)B_DIM * T_DIM * N_DIM;
  const long long WS  = (long long)H_DIM * H_DIM;     // 262144

  float* out = (float*)d_out;
  float* out_v   = out;
  float* out_t   = out + TBH;
  float* out_vnm = out + 2 * TBH;
  float* out_tnm = out + 2 * TBH + BTN;
  float* out_vta = out + 2 * TBH + 2 * BTN;
  float* out_tta = out_vta + NT_DIM * B_DIM;

  char* w = (char*)d_ws;
  auto alloc = [&](long long bytes) {
    char* p = w; w += (bytes + 255) & ~255LL; return p;
  };
  // WT slots: 0 WQv,1 WKv,2 WVv,3 WQt,4 WKt,5 WVt (raw), 6 WoTv,7 WoTt (trans)
  short* WT    = (short*)alloc(8 * WS * 2);
  short* Mv    = (short*)alloc(WS * 2);
  short* Mt    = (short*)alloc(WS * 2);
  short* PTv   = (short*)alloc(WS * 2);
  short* PTt   = (short*)alloc(WS * 2);
  short* Ac16v = (short*)alloc(1048576LL * 2);
  short* Ac16t = (short*)alloc(1048576LL * 2);
  short* Fr16v = (short*)alloc(TBH * 2);
  short* Fr16t = (short*)alloc(TBH * 2);
  short* KWTv  = (short*)alloc(8LL * 131072 * 2);  // [b][n][f]
  short* KWTt  = (short*)alloc(8LL * 131072 * 2);
  short* VWTv  = (short*)alloc(8LL * 131072 * 2);  // [b][g][n]
  short* VWTt  = (short*)alloc(8LL * 131072 * 2);
  short* Av    = (short*)alloc(BTN * 2);
  short* At    = (short*)alloc(BTN * 2);
  short* Lv    = (short*)alloc(BTN * 2);
  short* Lt    = (short*)alloc(BTN * 2);

  const float rsq = 0.044194173824159216f;  // 1/sqrt(512)

  // 1. weight prep: raw cvt (Wq,Wk,Wv x2) + transposed Wo x2
  {
    W6 s6 = {{(const float*)d_in[8], (const float*)d_in[9], (const float*)d_in[10],
              (const float*)d_in[12], (const float*)d_in[13], (const float*)d_in[14]}};
    rawcvt_kernel<<<dim3(128, 6), dim3(256), 0, stream>>>(s6, WT);
    W2 s2 = {{(const float*)d_in[11], (const float*)d_in[15]}};
    wtrans_kernel<<<dim3(16, 16, 2), dim3(32, 8), 0, stream>>>(s2, WT + 6 * WS);
  }

  // 2. action -> bf16, frame -> bf16
  ac16_kernel<<<dim3(512, 2), dim3(256), 0, stream>>>(v_action, t_action, Ac16v, Ac16t);
  fr16_kernel<<<dim3(8192, 2), dim3(256), 0, stream>>>(v_frame, t_frame, Fr16v, Fr16t);

  // 3. M = Wq@Wk^T and PT = WoT@Wv, 4 slots in one launch (z=0..3, zlog=0)
  {
    GP p = {{WT + 0 * WS, WT + 3 * WS, WT + 6 * WS, WT + 7 * WS},
            {WT + 1 * WS, WT + 4 * WS, WT + 2 * WS, WT + 5 * WS},
            {Mv, Mt, PTv, PTt},
            {nullptr, nullptr, nullptr, nullptr}};
    gemm_tn<short, false><<<dim3(4, 4, 4), dim3(256), 0, stream>>>(
        p, 0, 0LL, H_DIM, 0LL, H_DIM, 0LL, H_DIM, 512, 1.f);
  }

  // 4. KWT[b][n][f] = action @ M^T  (z = dom*8+b)
  {
    GP p = {{Ac16v, Ac16t}, {Mv, Mt}, {KWTv, KWTt}, {nullptr, nullptr}};
    gemm_tn<short, false><<<dim3(2, 4, 16), dim3(256), 0, stream>>>(
        p, 3, 512LL, B_DIM * H_DIM, 0LL, H_DIM, 131072LL, H_DIM, 512, 1.f);
  }

  // 5. VWT[b][g][n] = PT @ action^T  (z = dom*8+b)
  {
    GP p = {{PTv, PTt}, {Ac16v, Ac16t}, {VWTv, VWTt}, {nullptr, nullptr}};
    gemm_tn<short, false><<<dim3(4, 2, 16), dim3(256), 0, stream>>>(
        p, 3, 0LL, H_DIM, 512LL, B_DIM * H_DIM, 131072LL, N_DIM, 512, 1.f);
  }

  // 6. logits (bf16) [B,T,N] = Fr16 @ KWT^T  (bf16 pipeline, FLAT swizzle)
  {
    GP p = {{Fr16v, Fr16t}, {KWTv, KWTt}, {Lv, Lt}, {nullptr, nullptr}};
    gemm_tn<short, false, true><<<dim3(32 * 2 * 16), dim3(256), 0, stream>>>(
        p, 3, 512LL, B_DIM * H_DIM, 131072LL, H_DIM,
        (long long)T_DIM * N_DIM, N_DIM, 512, rsq, 32, 2);
  }

  // 7. fused combine + softmax + nomask-transpose
  softmax_fused<<<dim3(T_DIM / 16, B_DIM), dim3(256), 0, stream>>>(
      Lv, Lt, v_mask, t_mask, v_aw, t_aw, Av, At, out_vnm, out_tnm);

  // 8. out = attn @ VW + Fr16  (K=256, FLAT swizzle; residual from bf16 frame)
  {
    GP p = {{Av, At}, {VWTv, VWTt}, {out_v, out_t}, {Fr16v, Fr16t}};
    gemm_tn<float, true, true><<<dim3(32 * 4 * 16), dim3(256), 0, stream>>>(
        p, 3, (long long)T_DIM * N_DIM, N_DIM, 131072LL, N_DIM,
        512LL, B_DIM * H_DIM, 256, 1.f, 32, 4);
  }

  // 9. task heads
  task_kernel<<<dim3(1), dim3(1024), 0, stream>>>(
      v_task, t_task, v_tw, v_tb, t_tw, t_tb, out_vta, out_tta);
}